// Round 5
// baseline (657.380 us; speedup 1.0000x reference)
//
#include <hip/hip_runtime.h>
#include <stdint.h>

typedef unsigned short u16;
typedef __attribute__((ext_vector_type(8))) short v8s;   // 8 x bf16 (as raw shorts)
typedef __attribute__((ext_vector_type(4))) float v4f;   // MFMA accumulator

#define T_TOK 16384
#define DIM   768
#define NE    8
#define HH    3072
#define CH    1536      // H chunk
#define NCH   2
#define MCAP  33792     // max padded slot rows (32768 + 8*127, rounded to 128)

// ---- workspace layout (bytes) ----
#define O_W1T 0u            // 37,748,736  bf16 [E][H][D]
#define O_W2T 37748736u     // 37,748,736  bf16 [E][D][H]
#define O_XBF 75497472u     // 25,165,824  bf16 [T][D]
#define O_STK 100663296u    // MCAP*4 slot_token
#define O_SGT 100798464u    // MCAP*4 slot_gate
#define O_TE  100933632u    // T*2*4 expert ids
#define O_TG  101064704u    // T*2*4 gates
#define O_TS  101195776u    // T*2*4 token->slot
#define O_MET 101326848u    // counts/fill/offs
#define O_HBF 101327104u    // MCAP*CH*2 = 103,809,024
#define O_OBF 205136128u    // MCAP*DIM*2 = 51,904,512 (Tier A only)
#define WS_TIER_A 257040640ull

__device__ __forceinline__ u16 f2bf(float f){
  uint32_t u = __float_as_uint(f);
  uint32_t r = (u + 0x7fffu + ((u >> 16) & 1u)) >> 16;  // RNE
  return (u16)r;
}
__device__ __forceinline__ float bf2f(u16 v){
  return __uint_as_float(((uint32_t)v) << 16);
}
// async global->LDS, 16B per lane; LDS dest = wave-uniform base + lane*16
__device__ __forceinline__ void gll16(const u16* g, u16* l){
  __builtin_amdgcn_global_load_lds((const __attribute__((address_space(1))) uint32_t*)g,
                                   (__attribute__((address_space(3))) uint32_t*)l, 16, 0, 0);
}

// ================= weight transposes =================
__global__ void k_transposeW1(const float* __restrict__ W1, u16* __restrict__ W1t){
  __shared__ float tile[32][33];
  int e = blockIdx.z;
  int h0 = blockIdx.x * 32, d0 = blockIdx.y * 32;
  const float* src = W1 + (size_t)e * DIM * HH;     // [D][H]
  u16* dst = W1t + (size_t)e * HH * DIM;            // [H][D]
  int tx = threadIdx.x, ty = threadIdx.y;
  #pragma unroll
  for (int j = 0; j < 4; j++)
    tile[ty + 8*j][tx] = src[(size_t)(d0 + ty + 8*j) * HH + h0 + tx];
  __syncthreads();
  #pragma unroll
  for (int j = 0; j < 4; j++)
    dst[(size_t)(h0 + ty + 8*j) * DIM + d0 + tx] = f2bf(tile[tx][ty + 8*j]);
}

__global__ void k_transposeW2(const float* __restrict__ W2, u16* __restrict__ W2t){
  __shared__ float tile[32][33];
  int e = blockIdx.z;
  int d0 = blockIdx.x * 32, h0 = blockIdx.y * 32;
  const float* src = W2 + (size_t)e * HH * DIM;     // [H][D]
  u16* dst = W2t + (size_t)e * DIM * HH;            // [D][H]
  int tx = threadIdx.x, ty = threadIdx.y;
  #pragma unroll
  for (int j = 0; j < 4; j++)
    tile[ty + 8*j][tx] = src[(size_t)(h0 + ty + 8*j) * DIM + d0 + tx];
  __syncthreads();
  #pragma unroll
  for (int j = 0; j < 4; j++)
    dst[(size_t)(d0 + ty + 8*j) * HH + h0 + tx] = f2bf(tile[tx][ty + 8*j]);
}

// ================= router (no atomics; also emits Xbf = bf16(x)) =================
__global__ __launch_bounds__(256) void k_router(
    const float* __restrict__ x, const float* __restrict__ Wg, const float* __restrict__ bg,
    int* __restrict__ tE, float* __restrict__ tG, u16* __restrict__ Xbf){
  int t = blockIdx.x * 4 + (threadIdx.x >> 6);
  int l = threadIdx.x & 63;
  const float* xr = x + (size_t)t * DIM;
  u16* xb = Xbf + (size_t)t * DIM;
  float acc[NE];
  #pragma unroll
  for (int e = 0; e < NE; e++) acc[e] = 0.f;
  #pragma unroll
  for (int j = 0; j < DIM / 64; j++){
    int c = l + 64 * j;
    float xv = xr[c];
    xb[c] = f2bf(xv);                       // fused cast (replaces k_castX)
    const float4* wr4 = (const float4*)(Wg + (size_t)c * NE);
    float4 w0 = wr4[0], w1 = wr4[1];
    acc[0] += xv * w0.x; acc[1] += xv * w0.y; acc[2] += xv * w0.z; acc[3] += xv * w0.w;
    acc[4] += xv * w1.x; acc[5] += xv * w1.y; acc[6] += xv * w1.z; acc[7] += xv * w1.w;
  }
  #pragma unroll
  for (int off = 32; off; off >>= 1)
    #pragma unroll
    for (int e = 0; e < NE; e++) acc[e] += __shfl_xor(acc[e], off, 64);

  if (l == 0){
    float lgt[NE];
    #pragma unroll
    for (int e = 0; e < NE; e++) lgt[e] = acc[e] + bg[e];

    int i0 = 0; float v0 = lgt[0];
    #pragma unroll
    for (int e = 1; e < NE; e++) if (lgt[e] > v0){ v0 = lgt[e]; i0 = e; }
    int i1 = -1; float v1 = -1e30f;
    #pragma unroll
    for (int e = 0; e < NE; e++) if (e != i0 && lgt[e] > v1){ v1 = lgt[e]; i1 = e; }

    float ed = expf(v1 - v0);            // <= 1
    float g1 = ed / (1.f + ed);
    float g0 = 1.f / (1.f + ed);

    tE[2*t] = i0; tE[2*t+1] = i1;
    tG[2*t] = g0; tG[2*t+1] = g1;
  }
}

// ================= count (register histogram) =================
__global__ __launch_bounds__(256) void k_count(const int* __restrict__ tE, int* __restrict__ counts){
  int i = blockIdx.x * blockDim.x + threadIdx.x;   // 32 x 256
  int c[NE];
  #pragma unroll
  for (int e = 0; e < NE; e++) c[e] = 0;
  for (int j = i; j < 2 * T_TOK; j += 32 * 256){
    int v = tE[j];
    #pragma unroll
    for (int e = 0; e < NE; e++) c[e] += (v == e);
  }
  #pragma unroll
  for (int off = 32; off; off >>= 1)
    #pragma unroll
    for (int e = 0; e < NE; e++) c[e] += __shfl_xor(c[e], off, 64);
  if ((threadIdx.x & 63) == 0){
    #pragma unroll
    for (int e = 0; e < NE; e++) atomicAdd(&counts[e], c[e]);
  }
}

__global__ void k_scan(const int* __restrict__ counts, int* __restrict__ offs){
  if (threadIdx.x == 0){
    int o = 0;
    for (int e = 0; e < NE; e++){ offs[e] = o; o += (counts[e] + 127) & ~127; }
    offs[NE] = o;
  }
}

// ================= scatter (ballot-rank, 8 atomics/block) =================
__global__ __launch_bounds__(256) void k_scatter(
    const int* __restrict__ tE, const float* __restrict__ tG,
    const int* __restrict__ offs, int* __restrict__ fill,
    int* __restrict__ slot_token, float* __restrict__ slot_gate, int* __restrict__ tSlot){
  int t = blockIdx.x * 256 + threadIdx.x;
  int lane = threadIdx.x & 63, w = threadIdx.x >> 6;
  int e0 = tE[2*t], e1 = tE[2*t+1];
  float g0 = tG[2*t], g1 = tG[2*t+1];

  __shared__ int wcnt[4][NE];
  __shared__ int woff[4][NE];
  __shared__ int bbase[NE];

  uint64_t below = (1ull << lane) - 1ull;
  int rank0 = 0, rank1 = 0;
  #pragma unroll
  for (int e = 0; e < NE; e++){
    uint64_t m0 = __ballot(e0 == e);
    uint64_t m1 = __ballot(e1 == e);
    int c0 = __popcll(m0);
    if (e0 == e) rank0 = __popcll(m0 & below);
    if (e1 == e) rank1 = c0 + __popcll(m1 & below);
    if (lane == 0) wcnt[w][e] = c0 + __popcll(m1);
  }
  __syncthreads();
  if (threadIdx.x < NE){
    int e = threadIdx.x;
    int s = 0;
    #pragma unroll
    for (int ww = 0; ww < 4; ww++){ woff[ww][e] = s; s += wcnt[ww][e]; }
    bbase[e] = atomicAdd(&fill[e], s);
  }
  __syncthreads();
  int p0 = offs[e0] + bbase[e0] + woff[w][e0] + rank0;
  slot_token[p0] = t; slot_gate[p0] = g0; tSlot[2*t] = p0;
  int p1 = offs[e1] + bbase[e1] + woff[w][e1] + rank1;
  slot_token[p1] = t; slot_gate[p1] = g1; tSlot[2*t+1] = p1;
}

// Tier B only: out init = g0*b2[e0] + g1*b2[e1]
__global__ void k_outinit(const int* __restrict__ tE, const float* __restrict__ tG,
                          const float* __restrict__ b2, float* __restrict__ out){
  int t = blockIdx.x;
  int e0 = tE[2*t], e1 = tE[2*t+1];
  float g0 = tG[2*t], g1 = tG[2*t+1];
  const float* r0 = b2 + (size_t)e0 * DIM;
  const float* r1 = b2 + (size_t)e1 * DIM;
  float* o = out + (size_t)t * DIM;
  #pragma unroll
  for (int j = 0; j < DIM / 256; j++){
    int c = threadIdx.x + 256 * j;
    o[c] = g0 * r0[c] + g1 * r1[c];
  }
}

// ==== grouped GEMMs: m97 staging + XCD swizzle + DOUBLE-BUFFERED single-barrier K-loop ====
// Pipeline per K-step: stage(buf^1, k+1) -> ds_read/MFMA on buf[cur] -> barrier
// (the pre-barrier vmcnt(0) drain waits on loads that overlapped the whole compute phase)

// GEMM1: H[slot][h] = relu(X[token] @ W1[e] + b1[e]) * gate   (K = DIM = 768)
__global__ __launch_bounds__(256) void k_gemm1(
    const u16* __restrict__ Xbf, const u16* __restrict__ W1t, const float* __restrict__ b1,
    const int* __restrict__ slot_token, const float* __restrict__ slot_gate,
    const int* __restrict__ offs, u16* __restrict__ Hbuf, int cbase)
{
  const int NWG = NE * 128 * (CH / 128);      // 12288
  const int CPX = NWG / 8;
  int bid = blockIdx.x;
  int swz = (bid & 7) * CPX + (bid >> 3);
  int e  = swz / (128 * (CH / 128));
  int rem = swz % (128 * (CH / 128));
  int mt = rem / (CH / 128);
  int nt = rem % (CH / 128);

  int mbase = offs[e];
  int pc = offs[e+1] - mbase;
  if (mt * 128 >= pc) return;
  int grb = mbase + mt * 128;
  int nb = nt * 128;              // col base within chunk
  int habs = cbase + nb;          // absolute h col base

  __shared__ u16 As[2][128 * 32];   // double-buffered, linear (global_load_lds dest)
  __shared__ u16 Bs[2][128 * 32];

  int tid = threadIdx.x;
  int w = tid >> 6, lane = tid & 63;
  int lrow = lane >> 2, lu = lane & 3;          // 16 rows x 4 x 16B per wave-call
  int r0 = w * 32 + lrow, r1 = r0 + 16;

  const u16* ga0 = Xbf + (size_t)slot_token[grb + r0] * DIM + lu * 8;
  const u16* ga1 = Xbf + (size_t)slot_token[grb + r1] * DIM + lu * 8;
  const u16* gb0 = W1t + ((size_t)e * HH + habs + r0) * DIM + lu * 8;
  const u16* gb1 = W1t + ((size_t)e * HH + habs + r1) * DIM + lu * 8;
  int dA0 = (w * 32) * 32, dA1 = (w * 32 + 16) * 32;

  int lm = lane & 15, lg = lane >> 4;
  int wr = (w >> 1) * 64, wc = (w & 1) * 64;
  int offA[4], offB[4];
  #pragma unroll
  for (int mi = 0; mi < 4; mi++) offA[mi] = (wr + mi*16 + lm) * 32 + lg * 8;
  #pragma unroll
  for (int ni = 0; ni < 4; ni++) offB[ni] = (wc + ni*16 + lm) * 32 + lg * 8;

  v4f acc[4][4];
  #pragma unroll
  for (int mi = 0; mi < 4; mi++)
    #pragma unroll
    for (int ni = 0; ni < 4; ni++) acc[mi][ni] = 0.f;

  const int nk = DIM / 32;  // 24
  // prologue: stage k=0 into buf 0
  gll16(ga0, &As[0][dA0]); gll16(ga1, &As[0][dA1]);
  gll16(gb0, &Bs[0][dA0]); gll16(gb1, &Bs[0][dA1]);
  __syncthreads();
  int cur = 0;
  for (int kb = 0; kb < nk; ++kb){
    if (kb + 1 < nk){                       // prefetch k+1 into the other buffer
      int o = (kb + 1) * 32;
      int nx = cur ^ 1;
      gll16(ga0 + o, &As[nx][dA0]); gll16(ga1 + o, &As[nx][dA1]);
      gll16(gb0 + o, &Bs[nx][dA0]); gll16(gb1 + o, &Bs[nx][dA1]);
    }
    const u16* bA = As[cur];
    const u16* bB = Bs[cur];
    v8s af[4], bb[4];
    #pragma unroll
    for (int mi = 0; mi < 4; mi++) af[mi] = *(const v8s*)(bA + offA[mi]);
    #pragma unroll
    for (int ni = 0; ni < 4; ni++) bb[ni] = *(const v8s*)(bB + offB[ni]);
    #pragma unroll
    for (int mi = 0; mi < 4; mi++)
      #pragma unroll
      for (int ni = 0; ni < 4; ni++)
        acc[mi][ni] = __builtin_amdgcn_mfma_f32_16x16x32_bf16(af[mi], bb[ni], acc[mi][ni], 0, 0, 0);
    __syncthreads();                        // drains prefetch (vmcnt) + reads (lgkm)
    cur ^= 1;
  }

  float b1v[4];
  #pragma unroll
  for (int ni = 0; ni < 4; ni++) b1v[ni] = b1[(size_t)e * HH + habs + wc + ni*16 + lm];
  #pragma unroll
  for (int mi = 0; mi < 4; mi++){
    int rbase = grb + wr + mi*16 + lg*4;
    float g[4];
    #pragma unroll
    for (int i = 0; i < 4; i++) g[i] = slot_gate[rbase + i];
    #pragma unroll
    for (int ni = 0; ni < 4; ni++){
      int col = nb + wc + ni*16 + lm;
      #pragma unroll
      for (int i = 0; i < 4; i++){
        float v = acc[mi][ni][i] + b1v[ni];
        v = fmaxf(v, 0.f) * g[i];
        Hbuf[(size_t)(rbase + i) * CH + col] = f2bf(v);
      }
    }
  }
}

// GEMM2: Oslot[slot][d] (+)= H[slot] @ W2[e][chunk]    (K = CH)
// mode 0: atomic-add into out (Tier B); mode 1: store Obuf; mode 2: non-atomic RMW add
__global__ __launch_bounds__(256) void k_gemm2(
    const u16* __restrict__ Hbuf, const u16* __restrict__ W2t,
    const int* __restrict__ slot_token, const int* __restrict__ offs,
    float* __restrict__ out, u16* __restrict__ Obuf, int cbase, int mode)
{
  const int NWG = NE * 128 * (DIM / 128);     // 6144
  const int CPX = NWG / 8;
  int bid = blockIdx.x;
  int swz = (bid & 7) * CPX + (bid >> 3);
  int e  = swz / (128 * (DIM / 128));
  int rem = swz % (128 * (DIM / 128));
  int mt = rem / (DIM / 128);
  int nt = rem % (DIM / 128);

  int mbase = offs[e];
  int pc = offs[e+1] - mbase;
  if (mt * 128 >= pc) return;
  int grb = mbase + mt * 128;
  int nb = nt * 128;              // d col base

  __shared__ u16 As[2][128 * 32];
  __shared__ u16 Bs[2][128 * 32];

  int tid = threadIdx.x;
  int w = tid >> 6, lane = tid & 63;
  int lrow = lane >> 2, lu = lane & 3;
  int r0 = w * 32 + lrow, r1 = r0 + 16;

  const u16* ga0 = Hbuf + (size_t)(grb + r0) * CH + lu * 8;
  const u16* ga1 = Hbuf + (size_t)(grb + r1) * CH + lu * 8;
  const u16* gb0 = W2t + ((size_t)e * DIM + nb + r0) * HH + cbase + lu * 8;
  const u16* gb1 = W2t + ((size_t)e * DIM + nb + r1) * HH + cbase + lu * 8;
  int dA0 = (w * 32) * 32, dA1 = (w * 32 + 16) * 32;

  int lm = lane & 15, lg = lane >> 4;
  int wr = (w >> 1) * 64, wc = (w & 1) * 64;
  int offA[4], offB[4];
  #pragma unroll
  for (int mi = 0; mi < 4; mi++) offA[mi] = (wr + mi*16 + lm) * 32 + lg * 8;
  #pragma unroll
  for (int ni = 0; ni < 4; ni++) offB[ni] = (wc + ni*16 + lm) * 32 + lg * 8;

  v4f acc[4][4];
  #pragma unroll
  for (int mi = 0; mi < 4; mi++)
    #pragma unroll
    for (int ni = 0; ni < 4; ni++) acc[mi][ni] = 0.f;

  const int nk = CH / 32;  // 48
  gll16(ga0, &As[0][dA0]); gll16(ga1, &As[0][dA1]);
  gll16(gb0, &Bs[0][dA0]); gll16(gb1, &Bs[0][dA1]);
  __syncthreads();
  int cur = 0;
  for (int kb = 0; kb < nk; ++kb){
    if (kb + 1 < nk){
      int o = (kb + 1) * 32;
      int nx = cur ^ 1;
      gll16(ga0 + o, &As[nx][dA0]); gll16(ga1 + o, &As[nx][dA1]);
      gll16(gb0 + o, &Bs[nx][dA0]); gll16(gb1 + o, &Bs[nx][dA1]);
    }
    const u16* bA = As[cur];
    const u16* bB = Bs[cur];
    v8s af[4], bb[4];
    #pragma unroll
    for (int mi = 0; mi < 4; mi++) af[mi] = *(const v8s*)(bA + offA[mi]);
    #pragma unroll
    for (int ni = 0; ni < 4; ni++) bb[ni] = *(const v8s*)(bB + offB[ni]);
    #pragma unroll
    for (int mi = 0; mi < 4; mi++)
      #pragma unroll
      for (int ni = 0; ni < 4; ni++)
        acc[mi][ni] = __builtin_amdgcn_mfma_f32_16x16x32_bf16(af[mi], bb[ni], acc[mi][ni], 0, 0, 0);
    __syncthreads();
    cur ^= 1;
  }

  if (mode == 0){
    #pragma unroll
    for (int mi = 0; mi < 4; mi++){
      int rbase = grb + wr + mi*16 + lg*4;
      int tok[4];
      #pragma unroll
      for (int i = 0; i < 4; i++) tok[i] = slot_token[rbase + i];
      #pragma unroll
      for (int ni = 0; ni < 4; ni++){
        int col = nb + wc + ni*16 + lm;
        #pragma unroll
        for (int i = 0; i < 4; i++)
          unsafeAtomicAdd(&out[(size_t)tok[i] * DIM + col], acc[mi][ni][i]);
      }
    }
  } else if (mode == 1){
    #pragma unroll
    for (int mi = 0; mi < 4; mi++){
      int rbase = grb + wr + mi*16 + lg*4;
      #pragma unroll
      for (int ni = 0; ni < 4; ni++){
        int col = nb + wc + ni*16 + lm;
        #pragma unroll
        for (int i = 0; i < 4; i++)
          Obuf[(size_t)(rbase + i) * DIM + col] = f2bf(acc[mi][ni][i]);
      }
    }
  } else {
    #pragma unroll
    for (int mi = 0; mi < 4; mi++){
      int rbase = grb + wr + mi*16 + lg*4;
      #pragma unroll
      for (int ni = 0; ni < 4; ni++){
        int col = nb + wc + ni*16 + lm;
        #pragma unroll
        for (int i = 0; i < 4; i++){
          size_t p = (size_t)(rbase + i) * DIM + col;
          Obuf[p] = f2bf(bf2f(Obuf[p]) + acc[mi][ni][i]);   // block-exclusive, no atomic needed
        }
      }
    }
  }
}

// Tier A combine: out[t] = Obuf[slot0] + Obuf[slot1] + g0*b2[e0] + g1*b2[e1]
__global__ __launch_bounds__(192) void k_combine(
    const u16* __restrict__ Obuf, const int* __restrict__ tSlot,
    const int* __restrict__ tE, const float* __restrict__ tG,
    const float* __restrict__ b2, float* __restrict__ out)
{
  int t = blockIdx.x;
  int l = threadIdx.x;            // 192 threads, 4 cols each
  int s0 = tSlot[2*t], s1 = tSlot[2*t+1];
  int e0 = tE[2*t], e1 = tE[2*t+1];
  float g0 = tG[2*t], g1 = tG[2*t+1];
  int c = l * 4;
  ushort4 a = *(const ushort4*)(Obuf + (size_t)s0 * DIM + c);
  ushort4 b = *(const ushort4*)(Obuf + (size_t)s1 * DIM + c);
  float4 bA = *(const float4*)(b2 + (size_t)e0 * DIM + c);
  float4 bB = *(const float4*)(b2 + (size_t)e1 * DIM + c);
  float4 r;
  r.x = bf2f(a.x) + bf2f(b.x) + g0 * bA.x + g1 * bB.x;
  r.y = bf2f(a.y) + bf2f(b.y) + g0 * bA.y + g1 * bB.y;
  r.z = bf2f(a.z) + bf2f(b.z) + g0 * bA.z + g1 * bB.z;
  r.w = bf2f(a.w) + bf2f(b.w) + g0 * bA.w + g1 * bB.w;
  *(float4*)(out + (size_t)t * DIM + c) = r;
}

// ================= launch =================
extern "C" void kernel_launch(void* const* d_in, const int* in_sizes, int n_in,
                              void* d_out, int out_size, void* d_ws, size_t ws_size,
                              hipStream_t stream)
{
  const float* x  = (const float*)d_in[0];
  const float* Wg = (const float*)d_in[1];
  const float* bg = (const float*)d_in[2];
  const float* W1 = (const float*)d_in[3];
  const float* b1 = (const float*)d_in[4];
  const float* W2 = (const float*)d_in[5];
  const float* b2 = (const float*)d_in[6];
  float* out = (float*)d_out;
  char* ws = (char*)d_ws;

  u16*   W1t        = (u16*)(ws + O_W1T);
  u16*   W2t        = (u16*)(ws + O_W2T);
  u16*   Xbf        = (u16*)(ws + O_XBF);
  u16*   Hbuf       = (u16*)(ws + O_HBF);
  u16*   Obuf       = (u16*)(ws + O_OBF);
  int*   slot_token = (int*)(ws + O_STK);
  float* slot_gate  = (float*)(ws + O_SGT);
  int*   tE         = (int*)(ws + O_TE);
  float* tG         = (float*)(ws + O_TG);
  int*   tSlot      = (int*)(ws + O_TS);
  int*   meta       = (int*)(ws + O_MET);
  int*   counts = meta;
  int*   fill   = meta + 8;
  int*   offs   = meta + 16;

  const bool tierA = (ws_size >= WS_TIER_A);

  // zero slot arrays (pad rows => token 0, gate 0) and counts/fill
  hipMemsetAsync(ws + O_STK, 0, O_TE - O_STK, stream);
  hipMemsetAsync(ws + O_MET, 0, 128, stream);

  k_transposeW1<<<dim3(HH/32, DIM/32, NE), dim3(32, 8), 0, stream>>>(W1, W1t);
  k_transposeW2<<<dim3(DIM/32, HH/32, NE), dim3(32, 8), 0, stream>>>(W2, W2t);

  k_router<<<T_TOK/4, 256, 0, stream>>>(x, Wg, bg, tE, tG, Xbf);
  k_count<<<32, 256, 0, stream>>>(tE, counts);
  k_scan<<<1, 1, 0, stream>>>(counts, offs);
  k_scatter<<<T_TOK/256, 256, 0, stream>>>(tE, tG, offs, fill, slot_token, slot_gate, tSlot);
  if (!tierA)
    k_outinit<<<T_TOK, 256, 0, stream>>>(tE, tG, b2, out);

  for (int c = 0; c < NCH; c++){
    k_gemm1<<<NE * 128 * (CH/128), 256, 0, stream>>>(Xbf, W1t, b1, slot_token, slot_gate, offs, Hbuf, c * CH);
    int mode = tierA ? (c == 0 ? 1 : 2) : 0;
    k_gemm2<<<NE * 128 * (DIM/128), 256, 0, stream>>>(Hbuf, W2t, slot_token, offs, out, Obuf, c * CH, mode);
  }
  if (tierA)
    k_combine<<<T_TOK, 192, 0, stream>>>(Obuf, tSlot, tE, tG, b2, out);
}

// Round 6
// 487.759 us; speedup vs baseline: 1.3478x; 1.3478x over previous
//
#include <hip/hip_runtime.h>
#include <stdint.h>

typedef unsigned short u16;
typedef __attribute__((ext_vector_type(8))) short v8s;   // 8 x bf16
typedef __attribute__((ext_vector_type(4))) float v4f;   // MFMA accumulator

#define T_TOK 16384
#define DIM   768
#define NE    8
#define HH    3072
#define CH    1536      // H chunk
#define NCH   2
#define MCAP  34816     // 32768 + 8*255 pad (256-row tiles), rounded up

// ---- workspace layout (bytes) ----
#define O_W1T 0u            // 37,748,736  bf16 [E][H][D]
#define O_W2T 37748736u     // 37,748,736  bf16 [E][D][H]
#define O_XBF 75497472u     // 25,165,824  bf16 [T][D]
#define O_STK 100663296u    // MCAP*4 slot_token
#define O_SGT 100802560u    // MCAP*4 slot_gate
#define O_TE  100941824u    // T*2*4 expert ids
#define O_TG  101072896u    // T*2*4 gates
#define O_TS  101203968u    // T*2*4 token->slot
#define O_MET 101335040u    // counts/fill/offs
#define O_HBF 101335296u    // MCAP*CH*2 = 106,954,752
#define O_OBF 208290048u    // MCAP*DIM*2 = 53,477,376 (Tier A only)
#define WS_TIER_A 261767424ull

__device__ __forceinline__ u16 f2bf(float f){
  uint32_t u = __float_as_uint(f);
  uint32_t r = (u + 0x7fffu + ((u >> 16) & 1u)) >> 16;  // RNE
  return (u16)r;
}
__device__ __forceinline__ float bf2f(u16 v){
  return __uint_as_float(((uint32_t)v) << 16);
}
// async global->LDS, 16B/lane; LDS dest = wave-uniform base + lane*16
__device__ __forceinline__ void gll16(const u16* g, u16* l){
  __builtin_amdgcn_global_load_lds((const __attribute__((address_space(1))) uint32_t*)g,
                                   (__attribute__((address_space(3))) uint32_t*)l, 16, 0, 0);
}

// raw barrier + compiler memory fences (no implicit vmcnt/lgkm drain)
#define BAR() do { asm volatile("" ::: "memory"); __builtin_amdgcn_s_barrier(); asm volatile("" ::: "memory"); } while(0)
#define WAIT_LGKM0() asm volatile("s_waitcnt lgkmcnt(0)" ::: "memory")
#define WAIT_VM4() asm volatile("s_waitcnt vmcnt(4)" ::: "memory")
#define WAIT_VM0() asm volatile("s_waitcnt vmcnt(0)" ::: "memory")

// ================= weight transposes =================
__global__ void k_transposeW1(const float* __restrict__ W1, u16* __restrict__ W1t){
  __shared__ float tile[32][33];
  int e = blockIdx.z;
  int h0 = blockIdx.x * 32, d0 = blockIdx.y * 32;
  const float* src = W1 + (size_t)e * DIM * HH;     // [D][H]
  u16* dst = W1t + (size_t)e * HH * DIM;            // [H][D]
  int tx = threadIdx.x, ty = threadIdx.y;
  #pragma unroll
  for (int j = 0; j < 4; j++)
    tile[ty + 8*j][tx] = src[(size_t)(d0 + ty + 8*j) * HH + h0 + tx];
  __syncthreads();
  #pragma unroll
  for (int j = 0; j < 4; j++)
    dst[(size_t)(h0 + ty + 8*j) * DIM + d0 + tx] = f2bf(tile[tx][ty + 8*j]);
}

__global__ void k_transposeW2(const float* __restrict__ W2, u16* __restrict__ W2t){
  __shared__ float tile[32][33];
  int e = blockIdx.z;
  int d0 = blockIdx.x * 32, h0 = blockIdx.y * 32;
  const float* src = W2 + (size_t)e * HH * DIM;     // [H][D]
  u16* dst = W2t + (size_t)e * DIM * HH;            // [D][H]
  int tx = threadIdx.x, ty = threadIdx.y;
  #pragma unroll
  for (int j = 0; j < 4; j++)
    tile[ty + 8*j][tx] = src[(size_t)(h0 + ty + 8*j) * DIM + d0 + tx];
  __syncthreads();
  #pragma unroll
  for (int j = 0; j < 4; j++)
    dst[(size_t)(d0 + ty + 8*j) * HH + h0 + tx] = f2bf(tile[tx][ty + 8*j]);
}

// ================= router (no atomics; also emits Xbf = bf16(x)) =================
__global__ __launch_bounds__(256) void k_router(
    const float* __restrict__ x, const float* __restrict__ Wg, const float* __restrict__ bg,
    int* __restrict__ tE, float* __restrict__ tG, u16* __restrict__ Xbf){
  int t = blockIdx.x * 4 + (threadIdx.x >> 6);
  int l = threadIdx.x & 63;
  const float* xr = x + (size_t)t * DIM;
  u16* xb = Xbf + (size_t)t * DIM;
  float acc[NE];
  #pragma unroll
  for (int e = 0; e < NE; e++) acc[e] = 0.f;
  #pragma unroll
  for (int j = 0; j < DIM / 64; j++){
    int c = l + 64 * j;
    float xv = xr[c];
    xb[c] = f2bf(xv);
    const float4* wr4 = (const float4*)(Wg + (size_t)c * NE);
    float4 w0 = wr4[0], w1 = wr4[1];
    acc[0] += xv * w0.x; acc[1] += xv * w0.y; acc[2] += xv * w0.z; acc[3] += xv * w0.w;
    acc[4] += xv * w1.x; acc[5] += xv * w1.y; acc[6] += xv * w1.z; acc[7] += xv * w1.w;
  }
  #pragma unroll
  for (int off = 32; off; off >>= 1)
    #pragma unroll
    for (int e = 0; e < NE; e++) acc[e] += __shfl_xor(acc[e], off, 64);

  if (l == 0){
    float lgt[NE];
    #pragma unroll
    for (int e = 0; e < NE; e++) lgt[e] = acc[e] + bg[e];
    int i0 = 0; float v0 = lgt[0];
    #pragma unroll
    for (int e = 1; e < NE; e++) if (lgt[e] > v0){ v0 = lgt[e]; i0 = e; }
    int i1 = -1; float v1 = -1e30f;
    #pragma unroll
    for (int e = 0; e < NE; e++) if (e != i0 && lgt[e] > v1){ v1 = lgt[e]; i1 = e; }
    float ed = expf(v1 - v0);
    float g1 = ed / (1.f + ed);
    float g0 = 1.f / (1.f + ed);
    tE[2*t] = i0; tE[2*t+1] = i1;
    tG[2*t] = g0; tG[2*t+1] = g1;
  }
}

// ================= count =================
__global__ __launch_bounds__(256) void k_count(const int* __restrict__ tE, int* __restrict__ counts){
  int i = blockIdx.x * blockDim.x + threadIdx.x;
  int c[NE];
  #pragma unroll
  for (int e = 0; e < NE; e++) c[e] = 0;
  for (int j = i; j < 2 * T_TOK; j += 32 * 256){
    int v = tE[j];
    #pragma unroll
    for (int e = 0; e < NE; e++) c[e] += (v == e);
  }
  #pragma unroll
  for (int off = 32; off; off >>= 1)
    #pragma unroll
    for (int e = 0; e < NE; e++) c[e] += __shfl_xor(c[e], off, 64);
  if ((threadIdx.x & 63) == 0){
    #pragma unroll
    for (int e = 0; e < NE; e++) atomicAdd(&counts[e], c[e]);
  }
}

__global__ void k_scan(const int* __restrict__ counts, int* __restrict__ offs){
  if (threadIdx.x == 0){
    int o = 0;
    for (int e = 0; e < NE; e++){ offs[e] = o; o += (counts[e] + 255) & ~255; }  // pad to 256 (BM)
    offs[NE] = o;
  }
}

// ================= scatter (ballot-rank, 8 atomics/block) =================
__global__ __launch_bounds__(256) void k_scatter(
    const int* __restrict__ tE, const float* __restrict__ tG,
    const int* __restrict__ offs, int* __restrict__ fill,
    int* __restrict__ slot_token, float* __restrict__ slot_gate, int* __restrict__ tSlot){
  int t = blockIdx.x * 256 + threadIdx.x;
  int lane = threadIdx.x & 63, w = threadIdx.x >> 6;
  int e0 = tE[2*t], e1 = tE[2*t+1];
  float g0 = tG[2*t], g1 = tG[2*t+1];

  __shared__ int wcnt[4][NE];
  __shared__ int woff[4][NE];
  __shared__ int bbase[NE];

  uint64_t below = (1ull << lane) - 1ull;
  int rank0 = 0, rank1 = 0;
  #pragma unroll
  for (int e = 0; e < NE; e++){
    uint64_t m0 = __ballot(e0 == e);
    uint64_t m1 = __ballot(e1 == e);
    int c0 = __popcll(m0);
    if (e0 == e) rank0 = __popcll(m0 & below);
    if (e1 == e) rank1 = c0 + __popcll(m1 & below);
    if (lane == 0) wcnt[w][e] = c0 + __popcll(m1);
  }
  __syncthreads();
  if (threadIdx.x < NE){
    int e = threadIdx.x;
    int s = 0;
    #pragma unroll
    for (int ww = 0; ww < 4; ww++){ woff[ww][e] = s; s += wcnt[ww][e]; }
    bbase[e] = atomicAdd(&fill[e], s);
  }
  __syncthreads();
  int p0 = offs[e0] + bbase[e0] + woff[w][e0] + rank0;
  slot_token[p0] = t; slot_gate[p0] = g0; tSlot[2*t] = p0;
  int p1 = offs[e1] + bbase[e1] + woff[w][e1] + rank1;
  slot_token[p1] = t; slot_gate[p1] = g1; tSlot[2*t+1] = p1;
}

// Tier B only: out init = g0*b2[e0] + g1*b2[e1]
__global__ void k_outinit(const int* __restrict__ tE, const float* __restrict__ tG,
                          const float* __restrict__ b2, float* __restrict__ out){
  int t = blockIdx.x;
  int e0 = tE[2*t], e1 = tE[2*t+1];
  float g0 = tG[2*t], g1 = tG[2*t+1];
  const float* r0 = b2 + (size_t)e0 * DIM;
  const float* r1 = b2 + (size_t)e1 * DIM;
  float* o = out + (size_t)t * DIM;
  #pragma unroll
  for (int j = 0; j < DIM / 256; j++){
    int c = threadIdx.x + 256 * j;
    o[c] = g0 * r0[c] + g1 * r1[c];
  }
}

// ======== 256x256 BK=64 8-wave phase-split grouped GEMMs (T1+T2+T3+T4+T5) ========
// LDS: A/B each 2buf x 2half x (128 x 64) bf16 = 128 KiB total. Swizzle: byte ^= (row&7)<<4
// (applied on ds_read addr; inverse-applied on global SOURCE addr since global_load_lds
// writes linearly — rule 21 both-sides pattern).
// Per K-tile (4 phases): ph0 {read A[m0-3],B[n0-1]; stage B0(k+1); q0} ph1 {read B[n2-3];
// stage B1(k+1); q1} ph2 {read A[m4-7]; q2; lgkm0} ph3 {stage A0,A1(k+2); q3; vmcnt(4)}.

#define ABASE(b,h) (((b)*2+(h))*8192)
#define BBASE(b,h) (32768 + ((b)*2+(h))*8192)
// swizzled ds_read elem offset within a half (ro = local row 0..127)
#define SWZE(ro,ks) (((((ro)*128) + (ks)*64 + lg*16) ^ (((lm)&7)<<4)) >> 1)

#define STAGE2(p0, p1, base, kk) do { \
  gll16((p0) + (kk), &lds[(base) + (w*2)*512]); \
  gll16((p1) + (kk), &lds[(base) + (w*2+1)*512]); } while(0)

#define MFMA_Q(MOFF, NOFF, BF) \
  __builtin_amdgcn_s_setprio(1); \
  _Pragma("unroll") \
  for (int mi = 0; mi < 4; mi++) \
    _Pragma("unroll") \
    for (int ni = 0; ni < 2; ni++) \
      _Pragma("unroll") \
      for (int ks = 0; ks < 2; ks++) \
        acc[(MOFF)+mi][(NOFF)+ni] = __builtin_amdgcn_mfma_f32_16x16x32_bf16(aF[mi][ks], BF[ni][ks], acc[(MOFF)+mi][(NOFF)+ni], 0, 0, 0); \
  __builtin_amdgcn_s_setprio(0);

// GEMM1: H[slot][h] = relu(X[token] @ W1[e] + b1[e]) * gate   (K = DIM = 768)
__global__ __launch_bounds__(512, 2) void k_gemm1(
    const u16* __restrict__ Xbf, const u16* __restrict__ W1t, const float* __restrict__ b1,
    const int* __restrict__ slot_token, const float* __restrict__ slot_gate,
    const int* __restrict__ offs, u16* __restrict__ Hbuf, int cbase)
{
  const int NT = CH / 256;                  // 6
  const int NWG = NE * 64 * NT;             // 3072
  int bid = blockIdx.x;
  int swz = (bid & 7) * (NWG / 8) + (bid >> 3);
  int e = swz / (64 * NT);
  int rem = swz % (64 * NT);
  int mt = rem / NT, ntile = rem % NT;

  int mbase = offs[e];
  int pc = offs[e+1] - mbase;
  if (mt * 256 >= pc) return;
  int grb = mbase + mt * 256;
  int nb = ntile * 256;
  int habs = cbase + nb;

  __shared__ __align__(16) u16 lds[65536];  // 128 KiB

  int tid = threadIdx.x, w = tid >> 6, lane = tid & 63;
  int wm = w >> 2, wn = w & 3, lm = lane & 15, lg = lane >> 4;
  int cbe = (((lane & 7) ^ (lane >> 3)) << 3);   // inverse-swizzled source col (elems)

  // staging source pointers (per lane)
  int rA00 = (w*2+0)*8 + (lane>>3), rA01 = (w*2+1)*8 + (lane>>3);
  const u16 *sA00 = Xbf + (size_t)slot_token[grb + rA00]       * DIM + cbe;
  const u16 *sA01 = Xbf + (size_t)slot_token[grb + rA01]       * DIM + cbe;
  const u16 *sA10 = Xbf + (size_t)slot_token[grb + 128 + rA00] * DIM + cbe;
  const u16 *sA11 = Xbf + (size_t)slot_token[grb + 128 + rA01] * DIM + cbe;
  const u16 *sB00 = W1t + ((size_t)e*HH + habs + rA00)       * DIM + cbe;
  const u16 *sB01 = W1t + ((size_t)e*HH + habs + rA01)       * DIM + cbe;
  const u16 *sB10 = W1t + ((size_t)e*HH + habs + 128 + rA00) * DIM + cbe;
  const u16 *sB11 = W1t + ((size_t)e*HH + habs + 128 + rA01) * DIM + cbe;

  v4f acc[8][4];
  #pragma unroll
  for (int mi = 0; mi < 8; mi++)
    #pragma unroll
    for (int ni = 0; ni < 4; ni++) acc[mi][ni] = 0.f;

  const int NTK = DIM / 64;   // 12
  // prologue: tile0 (A,B) -> buf0, A(1) -> buf1
  STAGE2(sA00, sA01, ABASE(0,0), 0);  STAGE2(sA10, sA11, ABASE(0,1), 0);
  STAGE2(sB00, sB01, BBASE(0,0), 0);  STAGE2(sB10, sB11, BBASE(0,1), 0);
  STAGE2(sA00, sA01, ABASE(1,0), 64); STAGE2(sA10, sA11, ABASE(1,1), 64);
  WAIT_VM4(); BAR();

  v8s aF[4][2], bF0[2][2], bF1[2][2];
  for (int k = 0; k < NTK; ++k){
    int cur = k & 1, nx = cur ^ 1;
    int ab = ABASE(cur, wm);
    int bb = BBASE(cur, wn >> 1);
    // ---- ph0: read A[m0-3], B[n0-1]; stage B0(k+1); q0
    #pragma unroll
    for (int mi = 0; mi < 4; mi++)
      #pragma unroll
      for (int ks = 0; ks < 2; ks++)
        aF[mi][ks] = *(const v8s*)&lds[ab + SWZE(mi*16 + lm, ks)];
    #pragma unroll
    for (int ni = 0; ni < 2; ni++)
      #pragma unroll
      for (int ks = 0; ks < 2; ks++)
        bF0[ni][ks] = *(const v8s*)&lds[bb + SWZE((wn&1)*64 + ni*16 + lm, ks)];
    if (k + 1 < NTK) STAGE2(sB00, sB01, BBASE(nx,0), (k+1)*64);
    MFMA_Q(0, 0, bF0);
    BAR();
    // ---- ph1: read B[n2-3]; stage B1(k+1); q1
    #pragma unroll
    for (int ni = 0; ni < 2; ni++)
      #pragma unroll
      for (int ks = 0; ks < 2; ks++)
        bF1[ni][ks] = *(const v8s*)&lds[bb + SWZE((wn&1)*64 + (2+ni)*16 + lm, ks)];
    if (k + 1 < NTK) STAGE2(sB10, sB11, BBASE(nx,1), (k+1)*64);
    MFMA_Q(0, 2, bF1);
    BAR();
    // ---- ph2: read A[m4-7]; q2
    #pragma unroll
    for (int mi = 0; mi < 4; mi++)
      #pragma unroll
      for (int ks = 0; ks < 2; ks++)
        aF[mi][ks] = *(const v8s*)&lds[ab + SWZE((4+mi)*16 + lm, ks)];
    MFMA_Q(4, 0, bF0);
    WAIT_LGKM0(); BAR();
    // ---- ph3: stage A(k+2) into buf cur; q3; counted vmcnt
    if (k + 2 < NTK){
      STAGE2(sA00, sA01, ABASE(cur,0), (k+2)*64);
      STAGE2(sA10, sA11, ABASE(cur,1), (k+2)*64);
    }
    MFMA_Q(4, 2, bF1);
    if (k + 2 < NTK) { WAIT_VM4(); } else { WAIT_VM0(); }
    BAR();
  }

  // epilogue: bias + relu + gate, write Hbuf chunk
  float b1v[4];
  #pragma unroll
  for (int ni = 0; ni < 4; ni++) b1v[ni] = b1[(size_t)e * HH + habs + wn*64 + ni*16 + lm];
  #pragma unroll
  for (int mi = 0; mi < 8; mi++){
    int rbase = grb + wm*128 + mi*16 + lg*4;
    float g[4];
    #pragma unroll
    for (int i = 0; i < 4; i++) g[i] = slot_gate[rbase + i];
    #pragma unroll
    for (int ni = 0; ni < 4; ni++){
      int col = nb + wn*64 + ni*16 + lm;
      #pragma unroll
      for (int i = 0; i < 4; i++){
        float v = acc[mi][ni][i] + b1v[ni];
        v = fmaxf(v, 0.f) * g[i];
        Hbuf[(size_t)(rbase + i) * CH + col] = f2bf(v);
      }
    }
  }
}

// GEMM2: Oslot[slot][d] (+)= H[slot] @ W2[e][chunk]    (K = CH)
// mode 0: atomic-add into out (Tier B); mode 1: store Obuf; mode 2: non-atomic RMW add
__global__ __launch_bounds__(512, 2) void k_gemm2(
    const u16* __restrict__ Hbuf, const u16* __restrict__ W2t,
    const int* __restrict__ slot_token, const int* __restrict__ offs,
    float* __restrict__ out, u16* __restrict__ Obuf, int cbase, int mode)
{
  const int NT = DIM / 256;                 // 3
  const int NWG = NE * 64 * NT;             // 1536
  int bid = blockIdx.x;
  int swz = (bid & 7) * (NWG / 8) + (bid >> 3);
  int e = swz / (64 * NT);
  int rem = swz % (64 * NT);
  int mt = rem / NT, ntile = rem % NT;

  int mbase = offs[e];
  int pc = offs[e+1] - mbase;
  if (mt * 256 >= pc) return;
  int grb = mbase + mt * 256;
  int nb = ntile * 256;

  __shared__ __align__(16) u16 lds[65536];

  int tid = threadIdx.x, w = tid >> 6, lane = tid & 63;
  int wm = w >> 2, wn = w & 3, lm = lane & 15, lg = lane >> 4;
  int cbe = (((lane & 7) ^ (lane >> 3)) << 3);

  int rA00 = (w*2+0)*8 + (lane>>3), rA01 = (w*2+1)*8 + (lane>>3);
  const u16 *sA00 = Hbuf + (size_t)(grb + rA00)       * CH + cbe;
  const u16 *sA01 = Hbuf + (size_t)(grb + rA01)       * CH + cbe;
  const u16 *sA10 = Hbuf + (size_t)(grb + 128 + rA00) * CH + cbe;
  const u16 *sA11 = Hbuf + (size_t)(grb + 128 + rA01) * CH + cbe;
  const u16 *sB00 = W2t + ((size_t)e*DIM + nb + rA00)       * HH + cbase + cbe;
  const u16 *sB01 = W2t + ((size_t)e*DIM + nb + rA01)       * HH + cbase + cbe;
  const u16 *sB10 = W2t + ((size_t)e*DIM + nb + 128 + rA00) * HH + cbase + cbe;
  const u16 *sB11 = W2t + ((size_t)e*DIM + nb + 128 + rA01) * HH + cbase + cbe;

  v4f acc[8][4];
  #pragma unroll
  for (int mi = 0; mi < 8; mi++)
    #pragma unroll
    for (int ni = 0; ni < 4; ni++) acc[mi][ni] = 0.f;

  const int NTK = CH / 64;   // 24
  STAGE2(sA00, sA01, ABASE(0,0), 0);  STAGE2(sA10, sA11, ABASE(0,1), 0);
  STAGE2(sB00, sB01, BBASE(0,0), 0);  STAGE2(sB10, sB11, BBASE(0,1), 0);
  STAGE2(sA00, sA01, ABASE(1,0), 64); STAGE2(sA10, sA11, ABASE(1,1), 64);
  WAIT_VM4(); BAR();

  v8s aF[4][2], bF0[2][2], bF1[2][2];
  for (int k = 0; k < NTK; ++k){
    int cur = k & 1, nx = cur ^ 1;
    int ab = ABASE(cur, wm);
    int bb = BBASE(cur, wn >> 1);
    #pragma unroll
    for (int mi = 0; mi < 4; mi++)
      #pragma unroll
      for (int ks = 0; ks < 2; ks++)
        aF[mi][ks] = *(const v8s*)&lds[ab + SWZE(mi*16 + lm, ks)];
    #pragma unroll
    for (int ni = 0; ni < 2; ni++)
      #pragma unroll
      for (int ks = 0; ks < 2; ks++)
        bF0[ni][ks] = *(const v8s*)&lds[bb + SWZE((wn&1)*64 + ni*16 + lm, ks)];
    if (k + 1 < NTK) STAGE2(sB00, sB01, BBASE(nx,0), (k+1)*64);
    MFMA_Q(0, 0, bF0);
    BAR();
    #pragma unroll
    for (int ni = 0; ni < 2; ni++)
      #pragma unroll
      for (int ks = 0; ks < 2; ks++)
        bF1[ni][ks] = *(const v8s*)&lds[bb + SWZE((wn&1)*64 + (2+ni)*16 + lm, ks)];
    if (k + 1 < NTK) STAGE2(sB10, sB11, BBASE(nx,1), (k+1)*64);
    MFMA_Q(0, 2, bF1);
    BAR();
    #pragma unroll
    for (int mi = 0; mi < 4; mi++)
      #pragma unroll
      for (int ks = 0; ks < 2; ks++)
        aF[mi][ks] = *(const v8s*)&lds[ab + SWZE((4+mi)*16 + lm, ks)];
    MFMA_Q(4, 0, bF0);
    WAIT_LGKM0(); BAR();
    if (k + 2 < NTK){
      STAGE2(sA00, sA01, ABASE(cur,0), (k+2)*64);
      STAGE2(sA10, sA11, ABASE(cur,1), (k+2)*64);
    }
    MFMA_Q(4, 2, bF1);
    if (k + 2 < NTK) { WAIT_VM4(); } else { WAIT_VM0(); }
    BAR();
  }

  if (mode == 0){
    #pragma unroll
    for (int mi = 0; mi < 8; mi++){
      int rbase = grb + wm*128 + mi*16 + lg*4;
      int tok[4];
      #pragma unroll
      for (int i = 0; i < 4; i++) tok[i] = slot_token[rbase + i];
      #pragma unroll
      for (int ni = 0; ni < 4; ni++){
        int col = nb + wn*64 + ni*16 + lm;
        #pragma unroll
        for (int i = 0; i < 4; i++)
          unsafeAtomicAdd(&out[(size_t)tok[i] * DIM + col], acc[mi][ni][i]);
      }
    }
  } else if (mode == 1){
    #pragma unroll
    for (int mi = 0; mi < 8; mi++){
      int rbase = grb + wm*128 + mi*16 + lg*4;
      #pragma unroll
      for (int ni = 0; ni < 4; ni++){
        int col = nb + wn*64 + ni*16 + lm;
        #pragma unroll
        for (int i = 0; i < 4; i++)
          Obuf[(size_t)(rbase + i) * DIM + col] = f2bf(acc[mi][ni][i]);
      }
    }
  } else {
    #pragma unroll
    for (int mi = 0; mi < 8; mi++){
      int rbase = grb + wm*128 + mi*16 + lg*4;
      #pragma unroll
      for (int ni = 0; ni < 4; ni++){
        int col = nb + wn*64 + ni*16 + lm;
        #pragma unroll
        for (int i = 0; i < 4; i++){
          size_t p = (size_t)(rbase + i) * DIM + col;
          Obuf[p] = f2bf(bf2f(Obuf[p]) + acc[mi][ni][i]);   // block-exclusive
        }
      }
    }
  }
}

// Tier A combine: out[t] = Obuf[slot0] + Obuf[slot1] + g0*b2[e0] + g1*b2[e1]
__global__ __launch_bounds__(192) void k_combine(
    const u16* __restrict__ Obuf, const int* __restrict__ tSlot,
    const int* __restrict__ tE, const float* __restrict__ tG,
    const float* __restrict__ b2, float* __restrict__ out)
{
  int t = blockIdx.x;
  int l = threadIdx.x;
  int s0 = tSlot[2*t], s1 = tSlot[2*t+1];
  int e0 = tE[2*t], e1 = tE[2*t+1];
  float g0 = tG[2*t], g1 = tG[2*t+1];
  int c = l * 4;
  ushort4 a = *(const ushort4*)(Obuf + (size_t)s0 * DIM + c);
  ushort4 b = *(const ushort4*)(Obuf + (size_t)s1 * DIM + c);
  float4 bA = *(const float4*)(b2 + (size_t)e0 * DIM + c);
  float4 bB = *(const float4*)(b2 + (size_t)e1 * DIM + c);
  float4 r;
  r.x = bf2f(a.x) + bf2f(b.x) + g0 * bA.x + g1 * bB.x;
  r.y = bf2f(a.y) + bf2f(b.y) + g0 * bA.y + g1 * bB.y;
  r.z = bf2f(a.z) + bf2f(b.z) + g0 * bA.z + g1 * bB.z;
  r.w = bf2f(a.w) + bf2f(b.w) + g0 * bA.w + g1 * bB.w;
  *(float4*)(out + (size_t)t * DIM + c) = r;
}

// ================= launch =================
extern "C" void kernel_launch(void* const* d_in, const int* in_sizes, int n_in,
                              void* d_out, int out_size, void* d_ws, size_t ws_size,
                              hipStream_t stream)
{
  const float* x  = (const float*)d_in[0];
  const float* Wg = (const float*)d_in[1];
  const float* bg = (const float*)d_in[2];
  const float* W1 = (const float*)d_in[3];
  const float* b1 = (const float*)d_in[4];
  const float* W2 = (const float*)d_in[5];
  const float* b2 = (const float*)d_in[6];
  float* out = (float*)d_out;
  char* ws = (char*)d_ws;

  u16*   W1t        = (u16*)(ws + O_W1T);
  u16*   W2t        = (u16*)(ws + O_W2T);
  u16*   Xbf        = (u16*)(ws + O_XBF);
  u16*   Hbuf       = (u16*)(ws + O_HBF);
  u16*   Obuf       = (u16*)(ws + O_OBF);
  int*   slot_token = (int*)(ws + O_STK);
  float* slot_gate  = (float*)(ws + O_SGT);
  int*   tE         = (int*)(ws + O_TE);
  float* tG         = (float*)(ws + O_TG);
  int*   tSlot      = (int*)(ws + O_TS);
  int*   meta       = (int*)(ws + O_MET);
  int*   counts = meta;
  int*   fill   = meta + 8;
  int*   offs   = meta + 16;

  const bool tierA = (ws_size >= WS_TIER_A);

  hipMemsetAsync(ws + O_STK, 0, O_TE - O_STK, stream);   // pad slots: token 0, gate 0
  hipMemsetAsync(ws + O_MET, 0, 128, stream);

  k_transposeW1<<<dim3(HH/32, DIM/32, NE), dim3(32, 8), 0, stream>>>(W1, W1t);
  k_transposeW2<<<dim3(DIM/32, HH/32, NE), dim3(32, 8), 0, stream>>>(W2, W2t);

  k_router<<<T_TOK/4, 256, 0, stream>>>(x, Wg, bg, tE, tG, Xbf);
  k_count<<<32, 256, 0, stream>>>(tE, counts);
  k_scan<<<1, 1, 0, stream>>>(counts, offs);
  k_scatter<<<T_TOK/256, 256, 0, stream>>>(tE, tG, offs, fill, slot_token, slot_gate, tSlot);
  if (!tierA)
    k_outinit<<<T_TOK, 256, 0, stream>>>(tE, tG, b2, out);

  for (int c = 0; c < NCH; c++){
    k_gemm1<<<NE * 64 * (CH/256), 512, 0, stream>>>(Xbf, W1t, b1, slot_token, slot_gate, offs, Hbuf, c * CH);
    int mode = tierA ? (c == 0 ? 1 : 2) : 0;
    k_gemm2<<<NE * 64 * (DIM/256), 512, 0, stream>>>(Hbuf, W2t, slot_token, offs, out, Obuf, c * CH, mode);
  }
  if (tierA)
    k_combine<<<T_TOK, 192, 0, stream>>>(Obuf, tSlot, tE, tG, b2, out);
}